// Round 1
// baseline (833.718 us; speedup 1.0000x reference)
//
#include <hip/hip_runtime.h>
#include <hip/hip_bf16.h>
#include <math.h>

// Problem dims
#define BB 16
#define NN 100
#define MAXNB 10
#define NBONDS 120
#define AF 82
#define BF 6
#define HH 300
#define BIN 11
#define DEPTH 3
#define KTOP 80

// ---------------------------------------------------------------------------
// Generic small GEMM: C[:, widx*300 + col] = act(A @ W_widx + bias + Add)
// All our GEMMs have Ncols == 300. Block: 320 threads (5 waves), 8 rows/block.
// grid.x = number of W matrices (outputs written at column offset widx*300),
// grid.y = ceil(M/8).
// ---------------------------------------------------------------------------
__global__ __launch_bounds__(320) void k_gemm300(
    const float* __restrict__ A, int M, int Kd,
    const float* __restrict__ W0, const float* __restrict__ W1,
    const float* __restrict__ W2, const float* __restrict__ W3,
    float* __restrict__ C, int ldc,
    const float* __restrict__ bias,
    const float* __restrict__ Add, int ldAdd, int addOff,
    int act)
{
    __shared__ float sa[8 * 300];   // max Kd = 300
    const int widx = blockIdx.x;
    const float* W = (widx == 0) ? W0 : (widx == 1) ? W1 : (widx == 2) ? W2 : W3;
    const int row0 = blockIdx.y * 8;
    const int tid = threadIdx.x;

    // Stage 8 rows of A into LDS
    const int tot = 8 * Kd;
    for (int idx = tid; idx < tot; idx += 320) {
        int r = idx / Kd;
        int k = idx - r * Kd;
        int row = row0 + r;
        sa[idx] = (row < M) ? A[row * Kd + k] : 0.f;
    }
    __syncthreads();

    const int col = tid;
    if (col < 300) {
        float acc[8] = {0.f, 0.f, 0.f, 0.f, 0.f, 0.f, 0.f, 0.f};
        for (int k = 0; k < Kd; k++) {
            float w = W[k * 300 + col];
#pragma unroll
            for (int r = 0; r < 8; r++)
                acc[r] = fmaf(sa[r * Kd + k], w, acc[r]);
        }
        const float bsv = bias ? bias[col] : 0.f;
#pragma unroll
        for (int r = 0; r < 8; r++) {
            int row = row0 + r;
            if (row < M) {
                float v = acc[r] + bsv;
                if (Add) v += Add[row * ldAdd + addOff + col];
                if (act) v = fmaxf(v, 0.f);
                C[row * ldc + widx * 300 + col] = v;
            }
        }
    }
}

// ---------------------------------------------------------------------------
// Neighbor aggregation for one depth step.
// HW layout per row (b*N+n), ld=1200: [0:300)=h@W_nei_atom, [300:600)=h@W_U2a,
// [600:900)=h@W_self, [900:1200)=h@W_U1a.
// FB layout per row (b*NBONDS+m), ld=600: [0:300)=fb@W_nei_bond, [300:600)=fb@W_U2b
// ---------------------------------------------------------------------------
__global__ __launch_bounds__(320) void k_neighbor(
    const float* __restrict__ HW, const float* __restrict__ FB,
    const int* __restrict__ atom_nb, const int* __restrict__ bond_nb,
    const float* __restrict__ mask_neis, const float* __restrict__ mask_atoms,
    const float* __restrict__ b_U2,
    float* __restrict__ local_out, float* __restrict__ nl_out)
{
    const int bn = blockIdx.x;            // b*N + n
    const int b = bn / NN;
    const int h = threadIdx.x;
    if (h >= HH) return;

    const int base = bn * MAXNB;
    float fnei = 0.f, nls = 0.f;
#pragma unroll
    for (int k = 0; k < MAXNB; k++) {
        int an = atom_nb[base + k];
        int bd = bond_nb[base + k];
        float m = mask_neis[base + k];
        const float* hwrow = HW + (size_t)(b * NN + an) * 1200;
        const float* fbrow = FB + (size_t)(b * NBONDS + bd) * 600;
        float v = hwrow[h] * fbrow[h];
        fnei = fmaf(m, v, fnei);
        float u = hwrow[300 + h] + fbrow[300 + h] + b_U2[h];
        nls = fmaf(m, fmaxf(u, 0.f), nls);
    }
    local_out[bn * HH + h] = fnei * HW[(size_t)bn * 1200 + 600 + h] * mask_atoms[bn];
    nl_out[bn * HH + h] = nls;
}

// ---------------------------------------------------------------------------
// Attention score per pair: att[p] = sigmoid( sum_h relu(LW_i+LW_j+bin@Wab+b_att)*Ws + bs )
// One wave per pair; 4 waves per block.
// LL rows have ld 600: [0:300) = LW = local@W_att_local
// ---------------------------------------------------------------------------
__global__ __launch_bounds__(256) void k_att(
    const float* __restrict__ LL, const float* __restrict__ binary_feats,
    const float* __restrict__ W_att_bin, const float* __restrict__ b_att,
    const float* __restrict__ W_att_score, const float* __restrict__ b_att_score,
    float* __restrict__ att)
{
    const int p = blockIdx.x * 4 + (threadIdx.x >> 6);
    const int lane = threadIdx.x & 63;
    const int b = p / (NN * NN);
    const int r = p - b * NN * NN;
    const int i = r / NN;
    const int j = r - i * NN;

    const float* lwi = LL + (size_t)(b * NN + i) * 600;
    const float* lwj = LL + (size_t)(b * NN + j) * 600;
    const float* bin = binary_feats + (size_t)p * BIN;

    float bv[BIN];
#pragma unroll
    for (int t = 0; t < BIN; t++) bv[t] = bin[t];

    float s = 0.f;
    for (int h = lane; h < HH; h += 64) {
        float t = lwi[h] + lwj[h] + b_att[h];
#pragma unroll
        for (int tt = 0; tt < BIN; tt++)
            t = fmaf(bv[tt], W_att_bin[tt * HH + h], t);
        s = fmaf(fmaxf(t, 0.f), W_att_score[h], s);
    }
#pragma unroll
    for (int off = 32; off > 0; off >>= 1)
        s += __shfl_down(s, off);
    if (lane == 0)
        att[p] = 1.f / (1.f + expf(-(s + b_att_score[0])));
}

// ---------------------------------------------------------------------------
// ctx[b,i,:] = sum_j att[b,i,j] * local[b,j,:]
// ---------------------------------------------------------------------------
__global__ __launch_bounds__(320) void k_ctx(
    const float* __restrict__ att, const float* __restrict__ local,
    float* __restrict__ ctx)
{
    const int bi = blockIdx.x;           // b*N + i
    const int b = bi / NN;
    const int tid = threadIdx.x;
    __shared__ float sa[NN];
    if (tid < NN) sa[tid] = att[bi * NN + tid];
    __syncthreads();
    if (tid < HH) {
        float acc = 0.f;
        for (int j = 0; j < NN; j++)
            acc = fmaf(sa[j], local[(size_t)(b * NN + j) * HH + tid], acc);
        ctx[(size_t)bi * HH + tid] = acc;
    }
}

// ---------------------------------------------------------------------------
// Final pair score: out[p] = b_out + sum_h relu(LPG_i+LPG_j+bin@Wpb+b_p)*W_out
// LPG = local@W_pl + ctx@W_pg (per-row), ld 300. One wave per pair.
// ---------------------------------------------------------------------------
__global__ __launch_bounds__(256) void k_final(
    const float* __restrict__ LPG, const float* __restrict__ binary_feats,
    const float* __restrict__ W_pb, const float* __restrict__ b_p,
    const float* __restrict__ W_out, const float* __restrict__ b_out,
    float* __restrict__ out)
{
    const int p = blockIdx.x * 4 + (threadIdx.x >> 6);
    const int lane = threadIdx.x & 63;
    const int b = p / (NN * NN);
    const int r = p - b * NN * NN;
    const int i = r / NN;
    const int j = r - i * NN;

    const float* gi = LPG + (size_t)(b * NN + i) * HH;
    const float* gj = LPG + (size_t)(b * NN + j) * HH;
    const float* bin = binary_feats + (size_t)p * BIN;

    float bv[BIN];
#pragma unroll
    for (int t = 0; t < BIN; t++) bv[t] = bin[t];

    float s = 0.f;
    for (int h = lane; h < HH; h += 64) {
        float t = gi[h] + gj[h] + b_p[h];
#pragma unroll
        for (int tt = 0; tt < BIN; tt++)
            t = fmaf(bv[tt], W_pb[tt * HH + h], t);
        s = fmaf(fmaxf(t, 0.f), W_out[h], s);
    }
#pragma unroll
    for (int off = 32; off > 0; off >>= 1)
        s += __shfl_down(s, off);
    if (lane == 0)
        out[p] = s + b_out[0];
}

// ---------------------------------------------------------------------------
// Top-K per batch: iterative max-extraction, ties -> lower index (jax semantics).
// Each thread holds 40 values in (unrolled) registers. 2 barriers per iter.
// Indices are written as their float values.
// ---------------------------------------------------------------------------
__global__ __launch_bounds__(256) void k_topk(
    const float* __restrict__ scores, float* __restrict__ topk_out)
{
    const int b = blockIdx.x;
    const int tid = threadIdx.x;
    const int lane = tid & 63;
    const int wid = tid >> 6;
    const float* sc = scores + (size_t)b * (NN * NN);
    const int base = tid * 40;

    float v[40];
#pragma unroll
    for (int r = 0; r < 40; r++) {
        int idx = base + r;
        v[r] = (idx < NN * NN) ? sc[idx] : -INFINITY;
    }

    __shared__ float swv[4];
    __shared__ int   swi[4];
    __shared__ float gwv;
    __shared__ int   gwi;

    for (int kk = 0; kk < KTOP; kk++) {
        // local best
        float bvv = -INFINITY;
        int bii = 0x7fffffff;
#pragma unroll
        for (int r = 0; r < 40; r++) {
            int idx = base + r;
            bool better = (v[r] > bvv) || (v[r] == bvv && idx < bii);
            if (better) { bvv = v[r]; bii = idx; }
        }
        // wave reduce
#pragma unroll
        for (int off = 32; off > 0; off >>= 1) {
            float ov = __shfl_down(bvv, off);
            int   oi = __shfl_down(bii, off);
            bool better = (ov > bvv) || (ov == bvv && oi < bii);
            if (better) { bvv = ov; bii = oi; }
        }
        if (lane == 0) { swv[wid] = bvv; swi[wid] = bii; }
        __syncthreads();
        if (tid == 0) {
            float Bv = swv[0]; int Bi = swi[0];
#pragma unroll
            for (int w = 1; w < 4; w++) {
                bool better = (swv[w] > Bv) || (swv[w] == Bv && swi[w] < Bi);
                if (better) { Bv = swv[w]; Bi = swi[w]; }
            }
            gwv = Bv; gwi = Bi;
            topk_out[b * KTOP + kk] = (float)Bi;
        }
        __syncthreads();
        const int rm = gwi;
#pragma unroll
        for (int r = 0; r < 40; r++) {
            if (base + r == rm) v[r] = -INFINITY;
        }
        // next-iteration swv write is hazard-free: gwi read above happens
        // before the swv write in program order, barrier after swv write
        // orders it against tid0's next gwi write.
    }
}

// ---------------------------------------------------------------------------
extern "C" void kernel_launch(void* const* d_in, const int* in_sizes, int n_in,
                              void* d_out, int out_size, void* d_ws, size_t ws_size,
                              hipStream_t stream) {
    const float* fatoms       = (const float*)d_in[0];
    const float* fbonds       = (const float*)d_in[1];
    const int*   atom_nb      = (const int*)d_in[2];
    const int*   bond_nb      = (const int*)d_in[3];
    // d_in[4] num_nbs, d_in[5] n_atoms: unused by reference math
    const float* binary_feats = (const float*)d_in[6];
    const float* mask_neis    = (const float*)d_in[7];
    const float* mask_atoms   = (const float*)d_in[8];
    // d_in[9] sparse_idx: natural (b,i,j) order by construction
    const float* W_atom       = (const float*)d_in[10];
    const float* W_nei_atom   = (const float*)d_in[11];
    const float* W_nei_bond   = (const float*)d_in[12];
    const float* W_self       = (const float*)d_in[13];
    const float* W_U2         = (const float*)d_in[14];
    const float* b_U2         = (const float*)d_in[15];
    const float* W_U1         = (const float*)d_in[16];
    const float* b_U1         = (const float*)d_in[17];
    const float* W_att_local  = (const float*)d_in[18];
    const float* W_att_bin    = (const float*)d_in[19];
    const float* b_att        = (const float*)d_in[20];
    const float* W_att_score  = (const float*)d_in[21];
    const float* b_att_score  = (const float*)d_in[22];
    const float* W_pl         = (const float*)d_in[23];
    const float* W_pg         = (const float*)d_in[24];
    const float* W_pb         = (const float*)d_in[25];
    const float* b_p          = (const float*)d_in[26];
    const float* W_out        = (const float*)d_in[27];
    const float* b_out        = (const float*)d_in[28];

    float* ws = (float*)d_ws;
    const int ROWS = BB * NN;            // 1600
    float* h     = ws;                                   // 1600*300
    float* HW    = h     + (size_t)ROWS * HH;            // 1600*1200
    float* FB    = HW    + (size_t)ROWS * 1200;          // 1920*600
    float* nl    = FB    + (size_t)BB * NBONDS * 600;    // 1600*300
    float* local = nl    + (size_t)ROWS * HH;            // 1600*300
    float* LL    = local + (size_t)ROWS * HH;            // 1600*600 [LW|LPL]
    float* ctx   = LL    + (size_t)ROWS * 600;           // 1600*300
    float* LPG   = ctx   + (size_t)ROWS * HH;            // 1600*300
    float* att   = LPG   + (size_t)ROWS * HH;            // 160000

    float* out = (float*)d_out;
    float* topk_out = out + (size_t)BB * NN * NN;

    // h = relu(fatoms @ W_atom)
    k_gemm300<<<dim3(1, 200), 320, 0, stream>>>(
        fatoms, ROWS, AF, W_atom, nullptr, nullptr, nullptr,
        h, HH, nullptr, nullptr, 0, 0, 1);

    // FB = fbonds @ [W_nei_bond | W_U2b]
    k_gemm300<<<dim3(2, 240), 320, 0, stream>>>(
        fbonds, BB * NBONDS, BF, W_nei_bond, W_U2 + 300 * 300, nullptr, nullptr,
        FB, 600, nullptr, nullptr, 0, 0, 0);

    for (int d = 0; d < DEPTH; d++) {
        int nW = (d == DEPTH - 1) ? 3 : 4;   // last depth: h-update unused
        // HW = h @ [W_nei_atom | W_U2a | W_self | W_U1a]
        k_gemm300<<<dim3(nW, 200), 320, 0, stream>>>(
            h, ROWS, HH, W_nei_atom, W_U2, W_self, W_U1,
            HW, 1200, nullptr, nullptr, 0, 0, 0);
        // gather + aggregate neighbors -> local, nl
        k_neighbor<<<dim3(ROWS), 320, 0, stream>>>(
            HW, FB, atom_nb, bond_nb, mask_neis, mask_atoms, b_U2, local, nl);
        if (d < DEPTH - 1) {
            // h = relu(HW[:,900:1200] + nl @ W_U1b + b_U1)
            k_gemm300<<<dim3(1, 200), 320, 0, stream>>>(
                nl, ROWS, HH, W_U1 + 300 * 300, nullptr, nullptr, nullptr,
                h, HH, b_U1, HW, 1200, 900, 1);
        }
    }

    // LL = local @ [W_att_local | W_pl]
    k_gemm300<<<dim3(2, 200), 320, 0, stream>>>(
        local, ROWS, HH, W_att_local, W_pl, nullptr, nullptr,
        LL, 600, nullptr, nullptr, 0, 0, 0);

    // att[b,i,j]
    k_att<<<dim3(BB * NN * NN / 4), 256, 0, stream>>>(
        LL, binary_feats, W_att_bin, b_att, W_att_score, b_att_score, att);

    // ctx = att @ local (per batch)
    k_ctx<<<dim3(ROWS), 320, 0, stream>>>(att, local, ctx);

    // LPG = ctx @ W_pg + LPL
    k_gemm300<<<dim3(1, 200), 320, 0, stream>>>(
        ctx, ROWS, HH, W_pg, nullptr, nullptr, nullptr,
        LPG, HH, nullptr, LL, 600, 300, 0);

    // pair scores
    k_final<<<dim3(BB * NN * NN / 4), 256, 0, stream>>>(
        LPG, binary_feats, W_pb, b_p, W_out, b_out, out);

    // top-k indices per batch (as float values)
    k_topk<<<dim3(BB), 256, 0, stream>>>(out, topk_out);
}

// Round 2
// 783.543 us; speedup vs baseline: 1.0640x; 1.0640x over previous
//
#include <hip/hip_runtime.h>
#include <hip/hip_bf16.h>
#include <math.h>

// Problem dims
#define BB 16
#define NN 100
#define MAXNB 10
#define NBONDS 120
#define AF 82
#define BF 6
#define HH 300
#define BIN 11
#define DEPTH 3
#define KTOP 80

// ---------------------------------------------------------------------------
// Generic small GEMM: C[:, widx*300 + col] = act(A @ W_widx + bias + Add)
// All our GEMMs have Ncols == 300. Block: 320 threads (5 waves), 8 rows/block.
// ---------------------------------------------------------------------------
__global__ __launch_bounds__(320) void k_gemm300(
    const float* __restrict__ A, int M, int Kd,
    const float* __restrict__ W0, const float* __restrict__ W1,
    const float* __restrict__ W2, const float* __restrict__ W3,
    float* __restrict__ C, int ldc,
    const float* __restrict__ bias,
    const float* __restrict__ Add, int ldAdd, int addOff,
    int act)
{
    __shared__ float sa[8 * 300];   // max Kd = 300
    const int widx = blockIdx.x;
    const float* W = (widx == 0) ? W0 : (widx == 1) ? W1 : (widx == 2) ? W2 : W3;
    const int row0 = blockIdx.y * 8;
    const int tid = threadIdx.x;

    const int tot = 8 * Kd;
    for (int idx = tid; idx < tot; idx += 320) {
        int r = idx / Kd;
        int k = idx - r * Kd;
        int row = row0 + r;
        sa[idx] = (row < M) ? A[row * Kd + k] : 0.f;
    }
    __syncthreads();

    const int col = tid;
    if (col < 300) {
        float acc[8] = {0.f, 0.f, 0.f, 0.f, 0.f, 0.f, 0.f, 0.f};
        for (int k = 0; k < Kd; k++) {
            float w = W[k * 300 + col];
#pragma unroll
            for (int r = 0; r < 8; r++)
                acc[r] = fmaf(sa[r * Kd + k], w, acc[r]);
        }
        const float bsv = bias ? bias[col] : 0.f;
#pragma unroll
        for (int r = 0; r < 8; r++) {
            int row = row0 + r;
            if (row < M) {
                float v = acc[r] + bsv;
                if (Add) v += Add[row * ldAdd + addOff + col];
                if (act) v = fmaxf(v, 0.f);
                C[row * ldc + widx * 300 + col] = v;
            }
        }
    }
}

// ---------------------------------------------------------------------------
// Neighbor aggregation for one depth step.
// HW per row (b*N+n), ld=1200: [0:300)=h@W_nei_atom, [300:600)=h@W_U2a,
// [600:900)=h@W_self, [900:1200)=h@W_U1a.
// FB per row (b*NBONDS+m), ld=600: [0:300)=fb@W_nei_bond, [300:600)=fb@W_U2b
// ---------------------------------------------------------------------------
__global__ __launch_bounds__(320) void k_neighbor(
    const float* __restrict__ HW, const float* __restrict__ FB,
    const int* __restrict__ atom_nb, const int* __restrict__ bond_nb,
    const float* __restrict__ mask_neis, const float* __restrict__ mask_atoms,
    const float* __restrict__ b_U2,
    float* __restrict__ local_out, float* __restrict__ nl_out)
{
    const int bn = blockIdx.x;            // b*N + n
    const int b = bn / NN;
    const int h = threadIdx.x;
    if (h >= HH) return;

    const int base = bn * MAXNB;
    float fnei = 0.f, nls = 0.f;
#pragma unroll
    for (int k = 0; k < MAXNB; k++) {
        int an = atom_nb[base + k];
        int bd = bond_nb[base + k];
        float m = mask_neis[base + k];
        const float* hwrow = HW + (size_t)(b * NN + an) * 1200;
        const float* fbrow = FB + (size_t)(b * NBONDS + bd) * 600;
        float v = hwrow[h] * fbrow[h];
        fnei = fmaf(m, v, fnei);
        float u = hwrow[300 + h] + fbrow[300 + h] + b_U2[h];
        nls = fmaf(m, fmaxf(u, 0.f), nls);
    }
    local_out[bn * HH + h] = fnei * HW[(size_t)bn * 1200 + 600 + h] * mask_atoms[bn];
    nl_out[bn * HH + h] = nls;
}

// ---------------------------------------------------------------------------
// Attention score per pair (float4-vectorized). One wave per pair, 4/block.
// LL rows ld 600: [0:300) = LW = local@W_att_local
// ---------------------------------------------------------------------------
__global__ __launch_bounds__(256) void k_att(
    const float* __restrict__ LL, const float* __restrict__ binary_feats,
    const float* __restrict__ W_att_bin, const float* __restrict__ b_att,
    const float* __restrict__ W_att_score, const float* __restrict__ b_att_score,
    float* __restrict__ att)
{
    const int p = blockIdx.x * 4 + (threadIdx.x >> 6);
    const int lane = threadIdx.x & 63;
    const int b = p / (NN * NN);
    const int r = p - b * NN * NN;
    const int i = r / NN;
    const int j = r - i * NN;

    const float4* lwi = (const float4*)(LL + (size_t)(b * NN + i) * 600);
    const float4* lwj = (const float4*)(LL + (size_t)(b * NN + j) * 600);
    const float4* ba4 = (const float4*)b_att;
    const float4* wb4 = (const float4*)W_att_bin;   // row stride 75 float4
    const float4* ws4 = (const float4*)W_att_score;
    const float* bin = binary_feats + (size_t)p * BIN;

    float bv[BIN];
#pragma unroll
    for (int t = 0; t < BIN; t++) bv[t] = bin[t];

    float s = 0.f;
#pragma unroll
    for (int it = 0; it < 2; it++) {
        const int h4 = it * 64 + lane;
        if (h4 < 75) {
            float4 a = lwi[h4];
            float4 c = lwj[h4];
            float4 d = ba4[h4];
            float tx = a.x + c.x + d.x;
            float ty = a.y + c.y + d.y;
            float tz = a.z + c.z + d.z;
            float tw = a.w + c.w + d.w;
#pragma unroll
            for (int tt = 0; tt < BIN; tt++) {
                float4 w = wb4[tt * 75 + h4];
                tx = fmaf(bv[tt], w.x, tx);
                ty = fmaf(bv[tt], w.y, ty);
                tz = fmaf(bv[tt], w.z, tz);
                tw = fmaf(bv[tt], w.w, tw);
            }
            float4 w = ws4[h4];
            s = fmaf(fmaxf(tx, 0.f), w.x, s);
            s = fmaf(fmaxf(ty, 0.f), w.y, s);
            s = fmaf(fmaxf(tz, 0.f), w.z, s);
            s = fmaf(fmaxf(tw, 0.f), w.w, s);
        }
    }
#pragma unroll
    for (int off = 32; off > 0; off >>= 1)
        s += __shfl_down(s, off);
    if (lane == 0)
        att[p] = 1.f / (1.f + expf(-(s + b_att_score[0])));
}

// ---------------------------------------------------------------------------
// ctx[b,i,:] = sum_j att[b,i,j] * local[b,j,:]
// ---------------------------------------------------------------------------
__global__ __launch_bounds__(320) void k_ctx(
    const float* __restrict__ att, const float* __restrict__ local,
    float* __restrict__ ctx)
{
    const int bi = blockIdx.x;           // b*N + i
    const int b = bi / NN;
    const int tid = threadIdx.x;
    __shared__ float sa[NN];
    if (tid < NN) sa[tid] = att[bi * NN + tid];
    __syncthreads();
    if (tid < HH) {
        float acc = 0.f;
        for (int j = 0; j < NN; j++)
            acc = fmaf(sa[j], local[(size_t)(b * NN + j) * HH + tid], acc);
        ctx[(size_t)bi * HH + tid] = acc;
    }
}

// ---------------------------------------------------------------------------
// Final pair score (float4-vectorized). One wave per pair, 4/block.
// LPG = local@W_pl + ctx@W_pg, ld 300.
// ---------------------------------------------------------------------------
__global__ __launch_bounds__(256) void k_final(
    const float* __restrict__ LPG, const float* __restrict__ binary_feats,
    const float* __restrict__ W_pb, const float* __restrict__ b_p,
    const float* __restrict__ W_out, const float* __restrict__ b_out,
    float* __restrict__ out)
{
    const int p = blockIdx.x * 4 + (threadIdx.x >> 6);
    const int lane = threadIdx.x & 63;
    const int b = p / (NN * NN);
    const int r = p - b * NN * NN;
    const int i = r / NN;
    const int j = r - i * NN;

    const float4* gi = (const float4*)(LPG + (size_t)(b * NN + i) * HH);
    const float4* gj = (const float4*)(LPG + (size_t)(b * NN + j) * HH);
    const float4* bp4 = (const float4*)b_p;
    const float4* wb4 = (const float4*)W_pb;        // row stride 75 float4
    const float4* wo4 = (const float4*)W_out;
    const float* bin = binary_feats + (size_t)p * BIN;

    float bv[BIN];
#pragma unroll
    for (int t = 0; t < BIN; t++) bv[t] = bin[t];

    float s = 0.f;
#pragma unroll
    for (int it = 0; it < 2; it++) {
        const int h4 = it * 64 + lane;
        if (h4 < 75) {
            float4 a = gi[h4];
            float4 c = gj[h4];
            float4 d = bp4[h4];
            float tx = a.x + c.x + d.x;
            float ty = a.y + c.y + d.y;
            float tz = a.z + c.z + d.z;
            float tw = a.w + c.w + d.w;
#pragma unroll
            for (int tt = 0; tt < BIN; tt++) {
                float4 w = wb4[tt * 75 + h4];
                tx = fmaf(bv[tt], w.x, tx);
                ty = fmaf(bv[tt], w.y, ty);
                tz = fmaf(bv[tt], w.z, tz);
                tw = fmaf(bv[tt], w.w, tw);
            }
            float4 w = wo4[h4];
            s = fmaf(fmaxf(tx, 0.f), w.x, s);
            s = fmaf(fmaxf(ty, 0.f), w.y, s);
            s = fmaf(fmaxf(tz, 0.f), w.z, s);
            s = fmaf(fmaxf(tw, 0.f), w.w, s);
        }
    }
#pragma unroll
    for (int off = 32; off > 0; off >>= 1)
        s += __shfl_down(s, off);
    if (lane == 0)
        out[p] = s + b_out[0];
}

// ---------------------------------------------------------------------------
// Top-K per batch via 4-pass radix select on monotone u32 keys in LDS.
// Ties -> lower index (jax semantics). Indices written as float values.
// One block (256 threads) per batch.
// ---------------------------------------------------------------------------
__global__ __launch_bounds__(256) void k_topk(
    const float* __restrict__ scores, float* __restrict__ topk_out)
{
    const int b = blockIdx.x;
    const int tid = threadIdx.x;
    const float* sc = scores + (size_t)b * (NN * NN);

    __shared__ unsigned int skey[NN * NN];      // 40 KB
    __shared__ unsigned int hist[256];
    __shared__ unsigned int candU[KTOP];
    __shared__ int candI[KTOP];
    __shared__ int cntG;
    __shared__ int curMin;
    __shared__ unsigned int sh_pref, sh_mask;
    __shared__ int sh_kRem;
    __shared__ int sh_last;

    // load + monotone key conversion (larger key <=> larger float)
    for (int idx = tid; idx < NN * NN; idx += 256) {
        unsigned int u = __float_as_uint(sc[idx]);
        u = (u & 0x80000000u) ? ~u : (u | 0x80000000u);
        skey[idx] = u;
    }
    if (tid == 0) {
        sh_pref = 0u; sh_mask = 0u; sh_kRem = KTOP; cntG = 0; sh_last = -1;
    }
    __syncthreads();

    // 4 passes, 8 bits each, from high byte down
    for (int pass = 0; pass < 4; pass++) {
        const int shift = 24 - 8 * pass;
        hist[tid] = 0u;
        __syncthreads();
        const unsigned int pref = sh_pref, mask = sh_mask;
        for (int idx = tid; idx < NN * NN; idx += 256) {
            unsigned int u = skey[idx];
            if ((u & mask) == pref)
                atomicAdd(&hist[(u >> shift) & 255u], 1u);
        }
        __syncthreads();
        if (tid == 0) {
            int c = 0, bsel = 0;
            const int k = sh_kRem;
            for (int bb = 255; bb >= 0; bb--) {
                c += (int)hist[bb];
                if (c >= k) { bsel = bb; break; }
            }
            sh_kRem = k - (c - (int)hist[bsel]);
            sh_pref = pref | ((unsigned int)bsel << shift);
            sh_mask = mask | (0xFFu << shift);
        }
        __syncthreads();
    }
    const unsigned int T = sh_pref;   // exact key of the KTOP-th largest

    // collect strictly-greater candidates (cntG = KTOP - sh_kRem <= 79)
    for (int idx = tid; idx < NN * NN; idx += 256) {
        unsigned int u = skey[idx];
        if (u > T) {
            int pos = atomicAdd(&cntG, 1);
            candU[pos] = u;
            candI[pos] = idx;
        }
    }
    __syncthreads();
    const int needE = KTOP - cntG;    // >= 1

    // take needE smallest indices among keys == T (1 iter in no-tie case)
    for (int e = 0; e < needE; e++) {
        if (tid == 0) curMin = 0x7fffffff;
        __syncthreads();
        const int last = sh_last;
        for (int idx = tid; idx < NN * NN; idx += 256) {
            if (skey[idx] == T && idx > last)
                atomicMin(&curMin, idx);
        }
        __syncthreads();
        if (tid == 0) {
            candU[cntG + e] = T;
            candI[cntG + e] = curMin;
            sh_last = curMin;
        }
        __syncthreads();
    }

    // O(K^2) rank sort: rank = #{others strictly ahead in (value desc, idx asc)}
    if (tid < KTOP) {
        const unsigned int mu = candU[tid];
        const int mi = candI[tid];
        int rank = 0;
        for (int o = 0; o < KTOP; o++) {
            unsigned int ou = candU[o];
            int oi = candI[o];
            if (ou > mu || (ou == mu && oi < mi)) rank++;
        }
        topk_out[b * KTOP + rank] = (float)mi;
    }
}

// ---------------------------------------------------------------------------
extern "C" void kernel_launch(void* const* d_in, const int* in_sizes, int n_in,
                              void* d_out, int out_size, void* d_ws, size_t ws_size,
                              hipStream_t stream) {
    const float* fatoms       = (const float*)d_in[0];
    const float* fbonds       = (const float*)d_in[1];
    const int*   atom_nb      = (const int*)d_in[2];
    const int*   bond_nb      = (const int*)d_in[3];
    const float* binary_feats = (const float*)d_in[6];
    const float* mask_neis    = (const float*)d_in[7];
    const float* mask_atoms   = (const float*)d_in[8];
    const float* W_atom       = (const float*)d_in[10];
    const float* W_nei_atom   = (const float*)d_in[11];
    const float* W_nei_bond   = (const float*)d_in[12];
    const float* W_self       = (const float*)d_in[13];
    const float* W_U2         = (const float*)d_in[14];
    const float* b_U2         = (const float*)d_in[15];
    const float* W_U1         = (const float*)d_in[16];
    const float* b_U1         = (const float*)d_in[17];
    const float* W_att_local  = (const float*)d_in[18];
    const float* W_att_bin    = (const float*)d_in[19];
    const float* b_att        = (const float*)d_in[20];
    const float* W_att_score  = (const float*)d_in[21];
    const float* b_att_score  = (const float*)d_in[22];
    const float* W_pl         = (const float*)d_in[23];
    const float* W_pg         = (const float*)d_in[24];
    const float* W_pb         = (const float*)d_in[25];
    const float* b_p          = (const float*)d_in[26];
    const float* W_out        = (const float*)d_in[27];
    const float* b_out        = (const float*)d_in[28];

    float* ws = (float*)d_ws;
    const int ROWS = BB * NN;            // 1600
    float* h     = ws;                                   // 1600*300
    float* HW    = h     + (size_t)ROWS * HH;            // 1600*1200
    float* FB    = HW    + (size_t)ROWS * 1200;          // 1920*600
    float* nl    = FB    + (size_t)BB * NBONDS * 600;    // 1600*300
    float* local = nl    + (size_t)ROWS * HH;            // 1600*300
    float* LL    = local + (size_t)ROWS * HH;            // 1600*600 [LW|LPL]
    float* ctx   = LL    + (size_t)ROWS * 600;           // 1600*300
    float* LPG   = ctx   + (size_t)ROWS * HH;            // 1600*300
    float* att   = LPG   + (size_t)ROWS * HH;            // 160000

    float* out = (float*)d_out;
    float* topk_out = out + (size_t)BB * NN * NN;

    // h = relu(fatoms @ W_atom)
    k_gemm300<<<dim3(1, 200), 320, 0, stream>>>(
        fatoms, ROWS, AF, W_atom, nullptr, nullptr, nullptr,
        h, HH, nullptr, nullptr, 0, 0, 1);

    // FB = fbonds @ [W_nei_bond | W_U2b]
    k_gemm300<<<dim3(2, 240), 320, 0, stream>>>(
        fbonds, BB * NBONDS, BF, W_nei_bond, W_U2 + 300 * 300, nullptr, nullptr,
        FB, 600, nullptr, nullptr, 0, 0, 0);

    for (int d = 0; d < DEPTH; d++) {
        int nW = (d == DEPTH - 1) ? 3 : 4;   // last depth: h-update unused
        // HW = h @ [W_nei_atom | W_U2a | W_self | W_U1a]
        k_gemm300<<<dim3(nW, 200), 320, 0, stream>>>(
            h, ROWS, HH, W_nei_atom, W_U2, W_self, W_U1,
            HW, 1200, nullptr, nullptr, 0, 0, 0);
        // gather + aggregate neighbors -> local, nl
        k_neighbor<<<dim3(ROWS), 320, 0, stream>>>(
            HW, FB, atom_nb, bond_nb, mask_neis, mask_atoms, b_U2, local, nl);
        if (d < DEPTH - 1) {
            // h = relu(HW[:,900:1200] + nl @ W_U1b + b_U1)
            k_gemm300<<<dim3(1, 200), 320, 0, stream>>>(
                nl, ROWS, HH, W_U1 + 300 * 300, nullptr, nullptr, nullptr,
                h, HH, b_U1, HW, 1200, 900, 1);
        }
    }

    // LL = local @ [W_att_local | W_pl]
    k_gemm300<<<dim3(2, 200), 320, 0, stream>>>(
        local, ROWS, HH, W_att_local, W_pl, nullptr, nullptr,
        LL, 600, nullptr, nullptr, 0, 0, 0);

    // att[b,i,j]
    k_att<<<dim3(BB * NN * NN / 4), 256, 0, stream>>>(
        LL, binary_feats, W_att_bin, b_att, W_att_score, b_att_score, att);

    // ctx = att @ local (per batch)
    k_ctx<<<dim3(ROWS), 320, 0, stream>>>(att, local, ctx);

    // LPG = ctx @ W_pg + LPL
    k_gemm300<<<dim3(1, 200), 320, 0, stream>>>(
        ctx, ROWS, HH, W_pg, nullptr, nullptr, nullptr,
        LPG, HH, nullptr, LL, 600, 300, 0);

    // pair scores
    k_final<<<dim3(BB * NN * NN / 4), 256, 0, stream>>>(
        LPG, binary_feats, W_pb, b_p, W_out, b_out, out);

    // top-k indices per batch (as float values)
    k_topk<<<dim3(BB), 256, 0, stream>>>(out, topk_out);
}

// Round 3
// 585.231 us; speedup vs baseline: 1.4246x; 1.3389x over previous
//
#include <hip/hip_runtime.h>
#include <hip/hip_bf16.h>
#include <math.h>

// Problem dims
#define BB 16
#define NN 100
#define MAXNB 10
#define NBONDS 120
#define AF 82
#define BF 6
#define HH 300
#define BIN 11
#define DEPTH 3
#define KTOP 80

// ---------------------------------------------------------------------------
// Generic small GEMM: C[:, widx*300 + col] = act(A @ W_widx + bias + Add)
// ---------------------------------------------------------------------------
__global__ __launch_bounds__(320) void k_gemm300(
    const float* __restrict__ A, int M, int Kd,
    const float* __restrict__ W0, const float* __restrict__ W1,
    const float* __restrict__ W2, const float* __restrict__ W3,
    float* __restrict__ C, int ldc,
    const float* __restrict__ bias,
    const float* __restrict__ Add, int ldAdd, int addOff,
    int act)
{
    __shared__ float sa[8 * 300];   // max Kd = 300
    const int widx = blockIdx.x;
    const float* W = (widx == 0) ? W0 : (widx == 1) ? W1 : (widx == 2) ? W2 : W3;
    const int row0 = blockIdx.y * 8;
    const int tid = threadIdx.x;

    const int tot = 8 * Kd;
    for (int idx = tid; idx < tot; idx += 320) {
        int r = idx / Kd;
        int k = idx - r * Kd;
        int row = row0 + r;
        sa[idx] = (row < M) ? A[row * Kd + k] : 0.f;
    }
    __syncthreads();

    const int col = tid;
    if (col < 300) {
        float acc[8] = {0.f, 0.f, 0.f, 0.f, 0.f, 0.f, 0.f, 0.f};
        for (int k = 0; k < Kd; k++) {
            float w = W[k * 300 + col];
#pragma unroll
            for (int r = 0; r < 8; r++)
                acc[r] = fmaf(sa[r * Kd + k], w, acc[r]);
        }
        const float bsv = bias ? bias[col] : 0.f;
#pragma unroll
        for (int r = 0; r < 8; r++) {
            int row = row0 + r;
            if (row < M) {
                float v = acc[r] + bsv;
                if (Add) v += Add[row * ldAdd + addOff + col];
                if (act) v = fmaxf(v, 0.f);
                C[row * ldc + widx * 300 + col] = v;
            }
        }
    }
}

// ---------------------------------------------------------------------------
// Neighbor aggregation for one depth step.
// HW per row (b*N+n), ld=1200: [0:300)=h@W_nei_atom, [300:600)=h@W_U2a,
// [600:900)=h@W_self, [900:1200)=h@W_U1a.
// FB per row (b*NBONDS+m), ld=600: [0:300)=fb@W_nei_bond, [300:600)=fb@W_U2b
// ---------------------------------------------------------------------------
__global__ __launch_bounds__(320) void k_neighbor(
    const float* __restrict__ HW, const float* __restrict__ FB,
    const int* __restrict__ atom_nb, const int* __restrict__ bond_nb,
    const float* __restrict__ mask_neis, const float* __restrict__ mask_atoms,
    const float* __restrict__ b_U2,
    float* __restrict__ local_out, float* __restrict__ nl_out)
{
    const int bn = blockIdx.x;            // b*N + n
    const int b = bn / NN;
    const int h = threadIdx.x;
    if (h >= HH) return;

    const int base = bn * MAXNB;
    float fnei = 0.f, nls = 0.f;
#pragma unroll
    for (int k = 0; k < MAXNB; k++) {
        int an = atom_nb[base + k];
        int bd = bond_nb[base + k];
        float m = mask_neis[base + k];
        const float* hwrow = HW + (size_t)(b * NN + an) * 1200;
        const float* fbrow = FB + (size_t)(b * NBONDS + bd) * 600;
        float v = hwrow[h] * fbrow[h];
        fnei = fmaf(m, v, fnei);
        float u = hwrow[300 + h] + fbrow[300 + h] + b_U2[h];
        nls = fmaf(m, fmaxf(u, 0.f), nls);
    }
    local_out[bn * HH + h] = fnei * HW[(size_t)bn * 1200 + 600 + h] * mask_atoms[bn];
    nl_out[bn * HH + h] = nls;
}

// ---------------------------------------------------------------------------
// Pair kernel (shared by attention-score and final-score passes).
// Block = 16x16 (i,j) tile for one batch; one THREAD per pair.
// Row vectors (LW or LPG) for the 32 tile rows staged in LDS; weight reads
// are wave-uniform float4 global loads (L1 broadcast).
//   u[h] = R_i[h] + R_j[h] + sum_tt bin[tt]*Wbin[tt][h] + bvec[h]
//   s    = sum_h relu(u[h]) * Wscore[h] + bscore
//   out  = mode==0 ? sigmoid(s) : s
// ---------------------------------------------------------------------------
__global__ __launch_bounds__(256) void k_pair(
    const float* __restrict__ R, int ldr,
    const float* __restrict__ binary_feats,
    const float* __restrict__ Wbin, const float* __restrict__ bvec,
    const float* __restrict__ Wscore, const float* __restrict__ bscore,
    float* __restrict__ outp, int mode)
{
    __shared__ float sLW[32 * 300];   // 38.4 KB
    const int i0 = blockIdx.x * 16;
    const int j0 = blockIdx.y * 16;
    const int b  = blockIdx.z;
    const int tid = threadIdx.x;

    // stage 16 i-rows + 16 j-rows into LDS (coalesced)
    for (int idx = tid; idx < 32 * 300; idx += 256) {
        int r = idx / 300;
        int c = idx - r * 300;
        int row = (r < 16) ? (i0 + r) : (j0 + (r - 16));
        float v = 0.f;
        if (row < NN) v = R[(size_t)(b * NN + row) * ldr + c];
        sLW[idx] = v;
    }
    __syncthreads();

    const int li = tid >> 4, lj = tid & 15;
    const int i = i0 + li, j = j0 + lj;
    const bool valid = (i < NN) && (j < NN);
    const int p = (b * NN + i) * NN + j;

    float bv[BIN];
    const float* bin = binary_feats + (size_t)(valid ? p : 0) * BIN;
#pragma unroll
    for (int t = 0; t < BIN; t++) bv[t] = bin[t];

    const float4* Ai = (const float4*)(sLW + li * 300);
    const float4* Aj = (const float4*)(sLW + (16 + lj) * 300);
    const float4* bv4 = (const float4*)bvec;
    const float4* wb4 = (const float4*)Wbin;     // row stride 75 float4
    const float4* ws4 = (const float4*)Wscore;

    float s = 0.f;
#pragma unroll 5
    for (int h4 = 0; h4 < 75; h4++) {
        float4 a = Ai[h4];
        float4 c = Aj[h4];
        float4 d = bv4[h4];
        float tx = a.x + c.x + d.x;
        float ty = a.y + c.y + d.y;
        float tz = a.z + c.z + d.z;
        float tw = a.w + c.w + d.w;
#pragma unroll
        for (int tt = 0; tt < BIN; tt++) {
            float4 w = wb4[tt * 75 + h4];
            tx = fmaf(bv[tt], w.x, tx);
            ty = fmaf(bv[tt], w.y, ty);
            tz = fmaf(bv[tt], w.z, tz);
            tw = fmaf(bv[tt], w.w, tw);
        }
        float4 w = ws4[h4];
        s = fmaf(fmaxf(tx, 0.f), w.x, s);
        s = fmaf(fmaxf(ty, 0.f), w.y, s);
        s = fmaf(fmaxf(tz, 0.f), w.z, s);
        s = fmaf(fmaxf(tw, 0.f), w.w, s);
    }
    s += bscore[0];
    if (valid)
        outp[p] = (mode == 0) ? (1.f / (1.f + expf(-s))) : s;
}

// ---------------------------------------------------------------------------
// ctx[b,i,:] = sum_j att[b,i,j] * local[b,j,:]
// ---------------------------------------------------------------------------
__global__ __launch_bounds__(320) void k_ctx(
    const float* __restrict__ att, const float* __restrict__ local,
    float* __restrict__ ctx)
{
    const int bi = blockIdx.x;           // b*N + i
    const int b = bi / NN;
    const int tid = threadIdx.x;
    __shared__ float sa[NN];
    if (tid < NN) sa[tid] = att[bi * NN + tid];
    __syncthreads();
    if (tid < HH) {
        float acc = 0.f;
        for (int j = 0; j < NN; j++)
            acc = fmaf(sa[j], local[(size_t)(b * NN + j) * HH + tid], acc);
        ctx[(size_t)bi * HH + tid] = acc;
    }
}

// ---------------------------------------------------------------------------
// Top-K per batch via 4-pass radix select on monotone u32 keys in LDS.
// ---------------------------------------------------------------------------
__global__ __launch_bounds__(256) void k_topk(
    const float* __restrict__ scores, float* __restrict__ topk_out)
{
    const int b = blockIdx.x;
    const int tid = threadIdx.x;
    const float* sc = scores + (size_t)b * (NN * NN);

    __shared__ unsigned int skey[NN * NN];      // 40 KB
    __shared__ unsigned int hist[256];
    __shared__ unsigned int candU[KTOP];
    __shared__ int candI[KTOP];
    __shared__ int cntG;
    __shared__ int curMin;
    __shared__ unsigned int sh_pref, sh_mask;
    __shared__ int sh_kRem;
    __shared__ int sh_last;

    for (int idx = tid; idx < NN * NN; idx += 256) {
        unsigned int u = __float_as_uint(sc[idx]);
        u = (u & 0x80000000u) ? ~u : (u | 0x80000000u);
        skey[idx] = u;
    }
    if (tid == 0) {
        sh_pref = 0u; sh_mask = 0u; sh_kRem = KTOP; cntG = 0; sh_last = -1;
    }
    __syncthreads();

    for (int pass = 0; pass < 4; pass++) {
        const int shift = 24 - 8 * pass;
        hist[tid] = 0u;
        __syncthreads();
        const unsigned int pref = sh_pref, mask = sh_mask;
        for (int idx = tid; idx < NN * NN; idx += 256) {
            unsigned int u = skey[idx];
            if ((u & mask) == pref)
                atomicAdd(&hist[(u >> shift) & 255u], 1u);
        }
        __syncthreads();
        if (tid == 0) {
            int c = 0, bsel = 0;
            const int k = sh_kRem;
            for (int bb = 255; bb >= 0; bb--) {
                c += (int)hist[bb];
                if (c >= k) { bsel = bb; break; }
            }
            sh_kRem = k - (c - (int)hist[bsel]);
            sh_pref = pref | ((unsigned int)bsel << shift);
            sh_mask = mask | (0xFFu << shift);
        }
        __syncthreads();
    }
    const unsigned int T = sh_pref;

    for (int idx = tid; idx < NN * NN; idx += 256) {
        unsigned int u = skey[idx];
        if (u > T) {
            int pos = atomicAdd(&cntG, 1);
            candU[pos] = u;
            candI[pos] = idx;
        }
    }
    __syncthreads();
    const int needE = KTOP - cntG;

    for (int e = 0; e < needE; e++) {
        if (tid == 0) curMin = 0x7fffffff;
        __syncthreads();
        const int last = sh_last;
        for (int idx = tid; idx < NN * NN; idx += 256) {
            if (skey[idx] == T && idx > last)
                atomicMin(&curMin, idx);
        }
        __syncthreads();
        if (tid == 0) {
            candU[cntG + e] = T;
            candI[cntG + e] = curMin;
            sh_last = curMin;
        }
        __syncthreads();
    }

    if (tid < KTOP) {
        const unsigned int mu = candU[tid];
        const int mi = candI[tid];
        int rank = 0;
        for (int o = 0; o < KTOP; o++) {
            unsigned int ou = candU[o];
            int oi = candI[o];
            if (ou > mu || (ou == mu && oi < mi)) rank++;
        }
        topk_out[b * KTOP + rank] = (float)mi;
    }
}

// ---------------------------------------------------------------------------
extern "C" void kernel_launch(void* const* d_in, const int* in_sizes, int n_in,
                              void* d_out, int out_size, void* d_ws, size_t ws_size,
                              hipStream_t stream) {
    const float* fatoms       = (const float*)d_in[0];
    const float* fbonds       = (const float*)d_in[1];
    const int*   atom_nb      = (const int*)d_in[2];
    const int*   bond_nb      = (const int*)d_in[3];
    const float* binary_feats = (const float*)d_in[6];
    const float* mask_neis    = (const float*)d_in[7];
    const float* mask_atoms   = (const float*)d_in[8];
    const float* W_atom       = (const float*)d_in[10];
    const float* W_nei_atom   = (const float*)d_in[11];
    const float* W_nei_bond   = (const float*)d_in[12];
    const float* W_self       = (const float*)d_in[13];
    const float* W_U2         = (const float*)d_in[14];
    const float* b_U2         = (const float*)d_in[15];
    const float* W_U1         = (const float*)d_in[16];
    const float* b_U1         = (const float*)d_in[17];
    const float* W_att_local  = (const float*)d_in[18];
    const float* W_att_bin    = (const float*)d_in[19];
    const float* b_att        = (const float*)d_in[20];
    const float* W_att_score  = (const float*)d_in[21];
    const float* b_att_score  = (const float*)d_in[22];
    const float* W_pl         = (const float*)d_in[23];
    const float* W_pg         = (const float*)d_in[24];
    const float* W_pb         = (const float*)d_in[25];
    const float* b_p          = (const float*)d_in[26];
    const float* W_out        = (const float*)d_in[27];
    const float* b_out        = (const float*)d_in[28];

    float* ws = (float*)d_ws;
    const int ROWS = BB * NN;            // 1600
    float* h     = ws;                                   // 1600*300
    float* HW    = h     + (size_t)ROWS * HH;            // 1600*1200
    float* FB    = HW    + (size_t)ROWS * 1200;          // 1920*600
    float* nl    = FB    + (size_t)BB * NBONDS * 600;    // 1600*300
    float* local = nl    + (size_t)ROWS * HH;            // 1600*300
    float* LL    = local + (size_t)ROWS * HH;            // 1600*600 [LW|LPL]
    float* ctx   = LL    + (size_t)ROWS * 600;           // 1600*300
    float* LPG   = ctx   + (size_t)ROWS * HH;            // 1600*300
    float* att   = LPG   + (size_t)ROWS * HH;            // 160000

    float* out = (float*)d_out;
    float* topk_out = out + (size_t)BB * NN * NN;

    // h = relu(fatoms @ W_atom)
    k_gemm300<<<dim3(1, 200), 320, 0, stream>>>(
        fatoms, ROWS, AF, W_atom, nullptr, nullptr, nullptr,
        h, HH, nullptr, nullptr, 0, 0, 1);

    // FB = fbonds @ [W_nei_bond | W_U2b]
    k_gemm300<<<dim3(2, 240), 320, 0, stream>>>(
        fbonds, BB * NBONDS, BF, W_nei_bond, W_U2 + 300 * 300, nullptr, nullptr,
        FB, 600, nullptr, nullptr, 0, 0, 0);

    for (int d = 0; d < DEPTH; d++) {
        int nW = (d == DEPTH - 1) ? 3 : 4;   // last depth: h-update unused
        // HW = h @ [W_nei_atom | W_U2a | W_self | W_U1a]
        k_gemm300<<<dim3(nW, 200), 320, 0, stream>>>(
            h, ROWS, HH, W_nei_atom, W_U2, W_self, W_U1,
            HW, 1200, nullptr, nullptr, 0, 0, 0);
        // gather + aggregate neighbors -> local, nl
        k_neighbor<<<dim3(ROWS), 320, 0, stream>>>(
            HW, FB, atom_nb, bond_nb, mask_neis, mask_atoms, b_U2, local, nl);
        if (d < DEPTH - 1) {
            // h = relu(HW[:,900:1200] + nl @ W_U1b + b_U1)
            k_gemm300<<<dim3(1, 200), 320, 0, stream>>>(
                nl, ROWS, HH, W_U1 + 300 * 300, nullptr, nullptr, nullptr,
                h, HH, b_U1, HW, 1200, 900, 1);
        }
    }

    // LL = local @ [W_att_local | W_pl]
    k_gemm300<<<dim3(2, 200), 320, 0, stream>>>(
        local, ROWS, HH, W_att_local, W_pl, nullptr, nullptr,
        LL, 600, nullptr, nullptr, 0, 0, 0);

    // att[b,i,j] — tiled pair kernel, mode 0 (sigmoid)
    k_pair<<<dim3(7, 7, BB), 256, 0, stream>>>(
        LL, 600, binary_feats, W_att_bin, b_att, W_att_score, b_att_score,
        att, 0);

    // ctx = att @ local (per batch)
    k_ctx<<<dim3(ROWS), 320, 0, stream>>>(att, local, ctx);

    // LPG = ctx @ W_pg + LPL
    k_gemm300<<<dim3(1, 200), 320, 0, stream>>>(
        ctx, ROWS, HH, W_pg, nullptr, nullptr, nullptr,
        LPG, HH, nullptr, LL, 600, 300, 0);

    // pair scores — tiled pair kernel, mode 1 (linear)
    k_pair<<<dim3(7, 7, BB), 256, 0, stream>>>(
        LPG, 300, binary_feats, W_pb, b_p, W_out, b_out,
        out, 1);

    // top-k indices per batch (as float values)
    k_topk<<<dim3(BB), 256, 0, stream>>>(out, topk_out);
}

// Round 4
// 487.555 us; speedup vs baseline: 1.7100x; 1.2003x over previous
//
#include <hip/hip_runtime.h>
#include <hip/hip_bf16.h>
#include <math.h>

// Problem dims
#define BB 16
#define NN 100
#define MAXNB 10
#define NBONDS 120
#define AF 82
#define BF 6
#define HH 300
#define BIN 11
#define DEPTH 3
#define KTOP 80

// ---------------------------------------------------------------------------
// k_gemm300 v2: register-blocked GEMM, C[:, widx*300+col] = act(A@W + bias + Add)
// Block = 320 threads = 80 col-quads x 4 row-groups. Tile: 16 rows x 300 cols.
// Each thread: 4 rows x 4 cols, ds_read_b128 A-fragments, float4 W loads.
// ---------------------------------------------------------------------------
__global__ __launch_bounds__(320) void k_gemm300(
    const float* __restrict__ A, int M, int Kd,
    const float* __restrict__ W0, const float* __restrict__ W1,
    const float* __restrict__ W2, const float* __restrict__ W3,
    float* __restrict__ C, int ldc,
    const float* __restrict__ bias,
    const float* __restrict__ Add, int ldAdd, int addOff,
    int act)
{
    __shared__ float sa[16 * 300];               // 19.2 KB max (Kd<=300)
    const int widx = blockIdx.x;
    const float* __restrict__ W =
        (widx == 0) ? W0 : (widx == 1) ? W1 : (widx == 2) ? W2 : W3;
    const int row0 = blockIdx.y * 16;
    const int tid = threadIdx.x;
    const int Kd4 = (Kd + 3) >> 2;
    const int ld  = Kd4 * 4;                     // padded LDS leading dim

    // ---- stage 16 rows of A into LDS (zero-padded) ----
    if ((Kd & 3) == 0) {
        const float4* A4 = (const float4*)A;
        float4* sa4 = (float4*)sa;
        const int tot4 = 16 * Kd4;
        for (int idx = tid; idx < tot4; idx += 320) {
            int r = idx / Kd4;
            int q = idx - r * Kd4;
            int row = row0 + r;
            float4 v = make_float4(0.f, 0.f, 0.f, 0.f);
            if (row < M) v = A4[(size_t)row * Kd4 + q];
            sa4[idx] = v;
        }
    } else {
        const int tot = 16 * ld;
        for (int idx = tid; idx < tot; idx += 320) {
            int r = idx / ld;
            int c = idx - r * ld;
            int row = row0 + r;
            float v = 0.f;
            if (row < M && c < Kd) v = A[(size_t)row * Kd + c];
            sa[idx] = v;
        }
    }
    __syncthreads();

    const int quad = tid % 80;                   // col-quad (0..79; 75 used)
    const int rowg = tid / 80;                   // 0..3 -> rows rowg*4..rowg*4+3
    const bool ok = (quad < 75);

    if (ok) {
        const float4* W4 = (const float4*)W;     // 75 float4 per W row
        const float4* sa4 = (const float4*)sa;
        float4 acc0 = make_float4(0.f,0.f,0.f,0.f);
        float4 acc1 = acc0, acc2 = acc0, acc3 = acc0;
        const int r0 = rowg * 4;
        const int kfull = Kd >> 2;

        for (int kc = 0; kc < kfull; kc++) {
            float4 w0 = W4[(size_t)(kc*4+0) * 75 + quad];
            float4 w1 = W4[(size_t)(kc*4+1) * 75 + quad];
            float4 w2 = W4[(size_t)(kc*4+2) * 75 + quad];
            float4 w3 = W4[(size_t)(kc*4+3) * 75 + quad];
            float4 a0 = sa4[(r0+0) * Kd4 + kc];
            float4 a1 = sa4[(r0+1) * Kd4 + kc];
            float4 a2 = sa4[(r0+2) * Kd4 + kc];
            float4 a3 = sa4[(r0+3) * Kd4 + kc];
#define GSTEP(ACC, AV) \
            ACC.x = fmaf(AV.x, w0.x, ACC.x); ACC.y = fmaf(AV.x, w0.y, ACC.y); \
            ACC.z = fmaf(AV.x, w0.z, ACC.z); ACC.w = fmaf(AV.x, w0.w, ACC.w); \
            ACC.x = fmaf(AV.y, w1.x, ACC.x); ACC.y = fmaf(AV.y, w1.y, ACC.y); \
            ACC.z = fmaf(AV.y, w1.z, ACC.z); ACC.w = fmaf(AV.y, w1.w, ACC.w); \
            ACC.x = fmaf(AV.z, w2.x, ACC.x); ACC.y = fmaf(AV.z, w2.y, ACC.y); \
            ACC.z = fmaf(AV.z, w2.z, ACC.z); ACC.w = fmaf(AV.z, w2.w, ACC.w); \
            ACC.x = fmaf(AV.w, w3.x, ACC.x); ACC.y = fmaf(AV.w, w3.y, ACC.y); \
            ACC.z = fmaf(AV.w, w3.z, ACC.z); ACC.w = fmaf(AV.w, w3.w, ACC.w);
            GSTEP(acc0, a0) GSTEP(acc1, a1) GSTEP(acc2, a2) GSTEP(acc3, a3)
        }
        if (Kd & 3) {                            // tail chunk (A-pad is zero)
            const int rem = Kd & 3;
            const float4 z = make_float4(0.f,0.f,0.f,0.f);
            float4 w0 = (rem > 0) ? W4[(size_t)(kfull*4+0) * 75 + quad] : z;
            float4 w1 = (rem > 1) ? W4[(size_t)(kfull*4+1) * 75 + quad] : z;
            float4 w2 = (rem > 2) ? W4[(size_t)(kfull*4+2) * 75 + quad] : z;
            float4 w3 = z;
            float4 a0 = sa4[(r0+0) * Kd4 + kfull];
            float4 a1 = sa4[(r0+1) * Kd4 + kfull];
            float4 a2 = sa4[(r0+2) * Kd4 + kfull];
            float4 a3 = sa4[(r0+3) * Kd4 + kfull];
            GSTEP(acc0, a0) GSTEP(acc1, a1) GSTEP(acc2, a2) GSTEP(acc3, a3)
#undef GSTEP
        }

        // ---- epilogue ----
        const int col = widx * 300 + quad * 4;
        float4 bsv = make_float4(0.f,0.f,0.f,0.f);
        if (bias) bsv = ((const float4*)bias)[quad];
        float4 accs[4] = {acc0, acc1, acc2, acc3};
#pragma unroll
        for (int i = 0; i < 4; i++) {
            int row = row0 + r0 + i;
            if (row < M) {
                float4 v = accs[i];
                v.x += bsv.x; v.y += bsv.y; v.z += bsv.z; v.w += bsv.w;
                if (Add) {
                    float4 ad = *(const float4*)(Add + (size_t)row * ldAdd + addOff + quad * 4);
                    v.x += ad.x; v.y += ad.y; v.z += ad.z; v.w += ad.w;
                }
                if (act) {
                    v.x = fmaxf(v.x, 0.f); v.y = fmaxf(v.y, 0.f);
                    v.z = fmaxf(v.z, 0.f); v.w = fmaxf(v.w, 0.f);
                }
                *(float4*)(C + (size_t)row * ldc + col) = v;
            }
        }
    }
}

// ---------------------------------------------------------------------------
// Neighbor aggregation for one depth step.
// HW per row (b*N+n), ld=1200: [0:300)=h@W_nei_atom, [300:600)=h@W_U2a,
// [600:900)=h@W_self, [900:1200)=h@W_U1a.
// FB per row (b*NBONDS+m), ld=600: [0:300)=fb@W_nei_bond, [300:600)=fb@W_U2b
// ---------------------------------------------------------------------------
__global__ __launch_bounds__(320) void k_neighbor(
    const float* __restrict__ HW, const float* __restrict__ FB,
    const int* __restrict__ atom_nb, const int* __restrict__ bond_nb,
    const float* __restrict__ mask_neis, const float* __restrict__ mask_atoms,
    const float* __restrict__ b_U2,
    float* __restrict__ local_out, float* __restrict__ nl_out)
{
    const int bn = blockIdx.x;            // b*N + n
    const int b = bn / NN;
    const int h = threadIdx.x;
    if (h >= HH) return;

    const int base = bn * MAXNB;
    float fnei = 0.f, nls = 0.f;
#pragma unroll
    for (int k = 0; k < MAXNB; k++) {
        int an = atom_nb[base + k];
        int bd = bond_nb[base + k];
        float m = mask_neis[base + k];
        const float* hwrow = HW + (size_t)(b * NN + an) * 1200;
        const float* fbrow = FB + (size_t)(b * NBONDS + bd) * 600;
        float v = hwrow[h] * fbrow[h];
        fnei = fmaf(m, v, fnei);
        float u = hwrow[300 + h] + fbrow[300 + h] + b_U2[h];
        nls = fmaf(m, fmaxf(u, 0.f), nls);
    }
    local_out[bn * HH + h] = fnei * HW[(size_t)bn * 1200 + 600 + h] * mask_atoms[bn];
    nl_out[bn * HH + h] = nls;
}

// ---------------------------------------------------------------------------
// Pair kernel (attention-score and final-score passes).
// Block = 16x16 (i,j) tile for one batch; one THREAD per pair.
// ---------------------------------------------------------------------------
__global__ __launch_bounds__(256) void k_pair(
    const float* __restrict__ R, int ldr,
    const float* __restrict__ binary_feats,
    const float* __restrict__ Wbin, const float* __restrict__ bvec,
    const float* __restrict__ Wscore, const float* __restrict__ bscore,
    float* __restrict__ outp, int mode)
{
    __shared__ float sLW[32 * 300];   // 38.4 KB
    const int i0 = blockIdx.x * 16;
    const int j0 = blockIdx.y * 16;
    const int b  = blockIdx.z;
    const int tid = threadIdx.x;

    for (int idx = tid; idx < 32 * 300; idx += 256) {
        int r = idx / 300;
        int c = idx - r * 300;
        int row = (r < 16) ? (i0 + r) : (j0 + (r - 16));
        float v = 0.f;
        if (row < NN) v = R[(size_t)(b * NN + row) * ldr + c];
        sLW[idx] = v;
    }
    __syncthreads();

    const int li = tid >> 4, lj = tid & 15;
    const int i = i0 + li, j = j0 + lj;
    const bool valid = (i < NN) && (j < NN);
    const int p = (b * NN + i) * NN + j;

    float bv[BIN];
    const float* bin = binary_feats + (size_t)(valid ? p : 0) * BIN;
#pragma unroll
    for (int t = 0; t < BIN; t++) bv[t] = bin[t];

    const float4* Ai = (const float4*)(sLW + li * 300);
    const float4* Aj = (const float4*)(sLW + (16 + lj) * 300);
    const float4* bv4 = (const float4*)bvec;
    const float4* wb4 = (const float4*)Wbin;     // row stride 75 float4
    const float4* ws4 = (const float4*)Wscore;

    float s = 0.f;
#pragma unroll 5
    for (int h4 = 0; h4 < 75; h4++) {
        float4 a = Ai[h4];
        float4 c = Aj[h4];
        float4 d = bv4[h4];
        float tx = a.x + c.x + d.x;
        float ty = a.y + c.y + d.y;
        float tz = a.z + c.z + d.z;
        float tw = a.w + c.w + d.w;
#pragma unroll
        for (int tt = 0; tt < BIN; tt++) {
            float4 w = wb4[tt * 75 + h4];
            tx = fmaf(bv[tt], w.x, tx);
            ty = fmaf(bv[tt], w.y, ty);
            tz = fmaf(bv[tt], w.z, tz);
            tw = fmaf(bv[tt], w.w, tw);
        }
        float4 w = ws4[h4];
        s = fmaf(fmaxf(tx, 0.f), w.x, s);
        s = fmaf(fmaxf(ty, 0.f), w.y, s);
        s = fmaf(fmaxf(tz, 0.f), w.z, s);
        s = fmaf(fmaxf(tw, 0.f), w.w, s);
    }
    s += bscore[0];
    if (valid)
        outp[p] = (mode == 0) ? (1.f / (1.f + expf(-s))) : s;
}

// ---------------------------------------------------------------------------
// ctx[b,i,:] = sum_j att[b,i,j] * local[b,j,:]; 4 i-rows per block.
// ---------------------------------------------------------------------------
__global__ __launch_bounds__(320) void k_ctx(
    const float* __restrict__ att, const float* __restrict__ local,
    float* __restrict__ ctx)
{
    const int bx = blockIdx.x;           // b*25 + (i0/4)
    const int b = bx / 25;
    const int i0 = (bx % 25) * 4;
    const int tid = threadIdx.x;
    __shared__ float sa[4 * NN];
    for (int idx = tid; idx < 4 * NN; idx += 320) {
        int ii = idx / NN, j = idx - ii * NN;
        sa[idx] = att[(size_t)(b * NN + i0 + ii) * NN + j];
    }
    __syncthreads();
    if (tid < HH) {
        float acc0 = 0.f, acc1 = 0.f, acc2 = 0.f, acc3 = 0.f;
        for (int j = 0; j < NN; j++) {
            float lv = local[(size_t)(b * NN + j) * HH + tid];
            acc0 = fmaf(sa[j], lv, acc0);
            acc1 = fmaf(sa[NN + j], lv, acc1);
            acc2 = fmaf(sa[2 * NN + j], lv, acc2);
            acc3 = fmaf(sa[3 * NN + j], lv, acc3);
        }
        ctx[(size_t)(b * NN + i0 + 0) * HH + tid] = acc0;
        ctx[(size_t)(b * NN + i0 + 1) * HH + tid] = acc1;
        ctx[(size_t)(b * NN + i0 + 2) * HH + tid] = acc2;
        ctx[(size_t)(b * NN + i0 + 3) * HH + tid] = acc3;
    }
}

// ---------------------------------------------------------------------------
// Top-K v2: 1024 threads/block, per-wave histograms, wave-parallel suffix-scan
// bin selection (no serial 256-bin loop). Ties -> lower index.
// ---------------------------------------------------------------------------
__global__ __launch_bounds__(1024) void k_topk(
    const float* __restrict__ scores, float* __restrict__ topk_out)
{
    const int b = blockIdx.x;
    const int tid = threadIdx.x;
    const int wid = tid >> 6;
    const int lane = tid & 63;
    const float* sc = scores + (size_t)b * (NN * NN);

    __shared__ unsigned int skey[NN * NN];      // 40 KB
    __shared__ unsigned int whist[16 * 256];    // 16 KB per-wave hists
    __shared__ unsigned int hist[256];
    __shared__ unsigned int candU[KTOP];
    __shared__ int candI[KTOP];
    __shared__ int cntG;
    __shared__ int curMin;
    __shared__ unsigned int sh_pref, sh_mask;
    __shared__ int sh_kRem;
    __shared__ int sh_last;

    for (int idx = tid; idx < NN * NN; idx += 1024) {
        unsigned int u = __float_as_uint(sc[idx]);
        u = (u & 0x80000000u) ? ~u : (u | 0x80000000u);
        skey[idx] = u;
    }
    if (tid == 0) {
        sh_pref = 0u; sh_mask = 0u; sh_kRem = KTOP; cntG = 0; sh_last = -1;
    }
    __syncthreads();

    for (int pass = 0; pass < 4; pass++) {
        const int shift = 24 - 8 * pass;
        unsigned int* wh = whist + (wid << 8);
        wh[lane] = 0u; wh[lane + 64] = 0u; wh[lane + 128] = 0u; wh[lane + 192] = 0u;
        __syncthreads();
        const unsigned int pref = sh_pref, mask = sh_mask;
        for (int idx = tid; idx < NN * NN; idx += 1024) {
            unsigned int u = skey[idx];
            if ((u & mask) == pref)
                atomicAdd(&wh[(u >> shift) & 255u], 1u);
        }
        __syncthreads();
        if (tid < 256) {
            unsigned int s = 0u;
#pragma unroll
            for (int w = 0; w < 16; w++) s += whist[(w << 8) | tid];
            hist[tid] = s;
        }
        __syncthreads();
        if (wid == 0) {
            // lane owns bins lane*4 .. lane*4+3
            unsigned int h0 = hist[lane * 4 + 0];
            unsigned int h1 = hist[lane * 4 + 1];
            unsigned int h2 = hist[lane * 4 + 2];
            unsigned int h3 = hist[lane * 4 + 3];
            unsigned int own = h0 + h1 + h2 + h3;
            unsigned int suf = own;               // inclusive suffix sum
#pragma unroll
            for (int off = 1; off < 64; off <<= 1) {
                unsigned int v = __shfl_down(suf, off);
                if (lane + off < 64) suf += v;
            }
            const int k = sh_kRem;
            const unsigned int above = suf - own; // count in bins > lane*4+3
            if (above < (unsigned int)k && suf >= (unsigned int)k) {
                unsigned int c = above, hb; int bsel;
                c += h3;
                if ((int)c >= k) { bsel = lane * 4 + 3; hb = h3; }
                else { c += h2;
                    if ((int)c >= k) { bsel = lane * 4 + 2; hb = h2; }
                    else { c += h1;
                        if ((int)c >= k) { bsel = lane * 4 + 1; hb = h1; }
                        else { c += h0; bsel = lane * 4; hb = h0; } } }
                sh_kRem = k - (int)(c - hb);
                sh_pref = pref | ((unsigned int)bsel << shift);
                sh_mask = mask | (0xFFu << shift);
            }
        }
        __syncthreads();
    }
    const unsigned int T = sh_pref;   // exact key of the KTOP-th largest

    for (int idx = tid; idx < NN * NN; idx += 1024) {
        unsigned int u = skey[idx];
        if (u > T) {
            int pos = atomicAdd(&cntG, 1);
            candU[pos] = u;
            candI[pos] = idx;
        }
    }
    __syncthreads();
    const int needE = KTOP - cntG;    // >= 1

    for (int e = 0; e < needE; e++) {
        if (tid == 0) curMin = 0x7fffffff;
        __syncthreads();
        const int last = sh_last;
        for (int idx = tid; idx < NN * NN; idx += 1024) {
            if (skey[idx] == T && idx > last)
                atomicMin(&curMin, idx);
        }
        __syncthreads();
        if (tid == 0) {
            candU[cntG + e] = T;
            candI[cntG + e] = curMin;
            sh_last = curMin;
        }
        __syncthreads();
    }

    if (tid < KTOP) {
        const unsigned int mu = candU[tid];
        const int mi = candI[tid];
        int rank = 0;
        for (int o = 0; o < KTOP; o++) {
            unsigned int ou = candU[o];
            int oi = candI[o];
            if (ou > mu || (ou == mu && oi < mi)) rank++;
        }
        topk_out[b * KTOP + rank] = (float)mi;
    }
}

// ---------------------------------------------------------------------------
extern "C" void kernel_launch(void* const* d_in, const int* in_sizes, int n_in,
                              void* d_out, int out_size, void* d_ws, size_t ws_size,
                              hipStream_t stream) {
    const float* fatoms       = (const float*)d_in[0];
    const float* fbonds       = (const float*)d_in[1];
    const int*   atom_nb      = (const int*)d_in[2];
    const int*   bond_nb      = (const int*)d_in[3];
    const float* binary_feats = (const float*)d_in[6];
    const float* mask_neis    = (const float*)d_in[7];
    const float* mask_atoms   = (const float*)d_in[8];
    const float* W_atom       = (const float*)d_in[10];
    const float* W_nei_atom   = (const float*)d_in[11];
    const float* W_nei_bond   = (const float*)d_in[12];
    const float* W_self       = (const float*)d_in[13];
    const float* W_U2         = (const float*)d_in[14];
    const float* b_U2         = (const float*)d_in[15];
    const float* W_U1         = (const float*)d_in[16];
    const float* b_U1         = (const float*)d_in[17];
    const float* W_att_local  = (const float*)d_in[18];
    const float* W_att_bin    = (const float*)d_in[19];
    const float* b_att        = (const float*)d_in[20];
    const float* W_att_score  = (const float*)d_in[21];
    const float* b_att_score  = (const float*)d_in[22];
    const float* W_pl         = (const float*)d_in[23];
    const float* W_pg         = (const float*)d_in[24];
    const float* W_pb         = (const float*)d_in[25];
    const float* b_p          = (const float*)d_in[26];
    const float* W_out        = (const float*)d_in[27];
    const float* b_out        = (const float*)d_in[28];

    float* ws = (float*)d_ws;
    const int ROWS = BB * NN;            // 1600
    float* h     = ws;                                   // 1600*300
    float* HW    = h     + (size_t)ROWS * HH;            // 1600*1200
    float* FB    = HW    + (size_t)ROWS * 1200;          // 1920*600
    float* nl    = FB    + (size_t)BB * NBONDS * 600;    // 1600*300
    float* local = nl    + (size_t)ROWS * HH;            // 1600*300
    float* LL    = local + (size_t)ROWS * HH;            // 1600*600 [LW|LPL]
    float* ctx   = LL    + (size_t)ROWS * 600;           // 1600*300
    float* LPG   = ctx   + (size_t)ROWS * HH;            // 1600*300
    float* att   = LPG   + (size_t)ROWS * HH;            // 160000

    float* out = (float*)d_out;
    float* topk_out = out + (size_t)BB * NN * NN;

    // h = relu(fatoms @ W_atom)
    k_gemm300<<<dim3(1, 100), 320, 0, stream>>>(
        fatoms, ROWS, AF, W_atom, nullptr, nullptr, nullptr,
        h, HH, nullptr, nullptr, 0, 0, 1);

    // FB = fbonds @ [W_nei_bond | W_U2b]
    k_gemm300<<<dim3(2, 120), 320, 0, stream>>>(
        fbonds, BB * NBONDS, BF, W_nei_bond, W_U2 + 300 * 300, nullptr, nullptr,
        FB, 600, nullptr, nullptr, 0, 0, 0);

    for (int d = 0; d < DEPTH; d++) {
        int nW = (d == DEPTH - 1) ? 3 : 4;   // last depth: h-update unused
        // HW = h @ [W_nei_atom | W_U2a | W_self | W_U1a]
        k_gemm300<<<dim3(nW, 100), 320, 0, stream>>>(
            h, ROWS, HH, W_nei_atom, W_U2, W_self, W_U1,
            HW, 1200, nullptr, nullptr, 0, 0, 0);
        // gather + aggregate neighbors -> local, nl
        k_neighbor<<<dim3(ROWS), 320, 0, stream>>>(
            HW, FB, atom_nb, bond_nb, mask_neis, mask_atoms, b_U2, local, nl);
        if (d < DEPTH - 1) {
            // h = relu(HW[:,900:1200] + nl @ W_U1b + b_U1)
            k_gemm300<<<dim3(1, 100), 320, 0, stream>>>(
                nl, ROWS, HH, W_U1 + 300 * 300, nullptr, nullptr, nullptr,
                h, HH, b_U1, HW, 1200, 900, 1);
        }
    }

    // LL = local @ [W_att_local | W_pl]
    k_gemm300<<<dim3(2, 100), 320, 0, stream>>>(
        local, ROWS, HH, W_att_local, W_pl, nullptr, nullptr,
        LL, 600, nullptr, nullptr, 0, 0, 0);

    // att[b,i,j] — tiled pair kernel, mode 0 (sigmoid)
    k_pair<<<dim3(7, 7, BB), 256, 0, stream>>>(
        LL, 600, binary_feats, W_att_bin, b_att, W_att_score, b_att_score,
        att, 0);

    // ctx = att @ local (per batch), 4 rows/block
    k_ctx<<<dim3(BB * 25), 320, 0, stream>>>(att, local, ctx);

    // LPG = ctx @ W_pg + LPL
    k_gemm300<<<dim3(1, 100), 320, 0, stream>>>(
        ctx, ROWS, HH, W_pg, nullptr, nullptr, nullptr,
        LPG, HH, nullptr, LL, 600, 300, 0);

    // pair scores — tiled pair kernel, mode 1 (linear)
    k_pair<<<dim3(7, 7, BB), 256, 0, stream>>>(
        LPG, 300, binary_feats, W_pb, b_p, W_out, b_out,
        out, 1);

    // top-k indices per batch (as float values)
    k_topk<<<dim3(BB), 1024, 0, stream>>>(out, topk_out);
}